// Round 2
// baseline (744.311 us; speedup 1.0000x reference)
//
#include <hip/hip_runtime.h>
#include <math.h>

// MoE top-2, D=1024, F=4096, E=8, T=4096 tokens.
// Pipeline: router -> pack rows per expert (128-aligned) -> bf16 grouped GEMM1
// (x @ W1 + b1, GELU) -> bf16 grouped GEMM2 (h @ W2 + b2, * routing weight,
// atomic scatter into out). Weights transposed+cast to bf16 [E][N][K] each
// launch so both MFMA operands are k-contiguous.
// R2: LDS XOR chunk-swizzle (kills 8-way bank conflicts under global_load_lds's
// fixed lane->slot mapping), fast sigmoid GELU epilogue, split-K=2 gemm2.

#define T_TOK 4096
#define DMODEL 1024
#define FDIM 4096
#define NEXP 8
#define MAXROWS 9216   // sum of round_up(count_e,128) <= 8192 + 8*127 = 9208
#define NRB 72         // MAXROWS / 128

typedef unsigned short u16;
typedef unsigned int u32;
typedef __attribute__((ext_vector_type(8))) short short8;
typedef __attribute__((ext_vector_type(4))) float f32x4;

// ---- workspace layout (bytes) ----
constexpr size_t OFF_CTRL   = 0;
constexpr size_t OFF_ROWMAP = 4096;                          // MAXROWS ints
constexpr size_t OFF_ROWW   = OFF_ROWMAP + (size_t)MAXROWS*4;   // MAXROWS floats
constexpr size_t OFF_TKIDX  = OFF_ROWW + (size_t)MAXROWS*4;     // T*2 ints
constexpr size_t OFF_TKW    = OFF_TKIDX + (size_t)T_TOK*2*4;    // T*2 floats
constexpr size_t OFF_XB     = 262144;                           // T*D bf16 = 8 MiB
constexpr size_t OFF_W1T    = OFF_XB + (size_t)T_TOK*DMODEL*2;      // E*F*D bf16
constexpr size_t OFF_W2T    = OFF_W1T + (size_t)NEXP*DMODEL*FDIM*2; // E*D*F bf16
constexpr size_t OFF_H      = OFF_W2T + (size_t)NEXP*FDIM*DMODEL*2; // MAXROWS*F bf16
constexpr size_t WS_NEED    = OFF_H + (size_t)MAXROWS*FDIM*2;       // ~208 MiB

__device__ __forceinline__ u16 f2bf(float f) {   // fp32 -> bf16, round-nearest-even
  u32 u = __float_as_uint(f);
  u += 0x7FFFu + ((u >> 16) & 1u);
  return (u16)(u >> 16);
}

__device__ __forceinline__ float fast_gelu(float v) {
  // gelu(v) = v * sigmoid(2u), u = 0.7978845608*(v + 0.044715 v^3)
  // max |diff vs exact erf-GELU| ~ 5e-4 — inside error budget.
  float u2 = v * (1.5957691216f + 0.0713548162f * v * v);   // 2u
  float s = __expf(-u2);
  return v * __builtin_amdgcn_rcpf(1.0f + s);
}

__device__ __forceinline__ void async16(void* lds, const void* g) {
  // wave-level: lane i's 16B land at lds_base + i*16 (wave-uniform lds base!)
  __builtin_amdgcn_global_load_lds((const __attribute__((address_space(1))) void*)g,
                                   (__attribute__((address_space(3))) void*)lds,
                                   16, 0, 0);
}

// ---- 1. cast x to bf16; init control state ----
__global__ void init_cast_kernel(const float* __restrict__ x, u16* __restrict__ xb,
                                 int* __restrict__ ctrl, int* __restrict__ rowmap) {
  int g = blockIdx.x * 256 + threadIdx.x;
  float4 v = ((const float4*)x)[g];
  u32 p0 = (u32)f2bf(v.x) | ((u32)f2bf(v.y) << 16);
  u32 p1 = (u32)f2bf(v.z) | ((u32)f2bf(v.w) << 16);
  ((uint2*)xb)[g] = make_uint2(p0, p1);
  if (g < NEXP) ctrl[g] = 0;
  if (g < MAXROWS) rowmap[g] = -1;
}

// ---- 2. router: fp32 logits, top-2, softmax ----
__global__ void router_kernel(const float* __restrict__ x, const float* __restrict__ Wr,
                              const float* __restrict__ br, int* __restrict__ ctrl,
                              int* __restrict__ tk_idx, float* __restrict__ tk_w) {
  int lane = threadIdx.x & 63, w = threadIdx.x >> 6;
  int t = blockIdx.x * 4 + w;
  const float* xt = x + (size_t)t * DMODEL;
  float acc[8] = {0.f,0.f,0.f,0.f,0.f,0.f,0.f,0.f};
  for (int i = 0; i < DMODEL / 64; i++) {
    int d = i * 64 + lane;
    float xv = xt[d];
    float4 w0 = *(const float4*)(Wr + d * 8);
    float4 w1 = *(const float4*)(Wr + d * 8 + 4);
    acc[0] += xv * w0.x; acc[1] += xv * w0.y; acc[2] += xv * w0.z; acc[3] += xv * w0.w;
    acc[4] += xv * w1.x; acc[5] += xv * w1.y; acc[6] += xv * w1.z; acc[7] += xv * w1.w;
  }
  #pragma unroll
  for (int off = 32; off > 0; off >>= 1)
    #pragma unroll
    for (int e = 0; e < 8; e++) acc[e] += __shfl_xor(acc[e], off);
  if (lane == 0) {
    float lg[8];
    #pragma unroll
    for (int e = 0; e < 8; e++) lg[e] = acc[e] + br[e];
    int e0 = 0;
    #pragma unroll
    for (int e = 1; e < 8; e++) if (lg[e] > lg[e0]) e0 = e;   // strict >: lowest idx wins ties
    int e1 = -1;
    #pragma unroll
    for (int e = 0; e < 8; e++) if (e != e0 && (e1 < 0 || lg[e] > lg[e1])) e1 = e;
    float p1 = __expf(lg[e1] - lg[e0]);
    float inv = 1.f / (1.f + p1);
    tk_idx[t*2] = e0; tk_idx[t*2+1] = e1;
    tk_w[t*2] = inv;  tk_w[t*2+1] = p1 * inv;
    atomicAdd(&ctrl[e0], 1); atomicAdd(&ctrl[e1], 1);
  }
}

// ---- 3. transpose+cast weights: [E][K][N] fp32 -> [E][N][K] bf16 ----
__global__ void transpose_cast_kernel(const float* __restrict__ in, u16* __restrict__ outp,
                                      int K, int N) {
  __shared__ float tile[64][65];
  int e = blockIdx.z;
  const float* src = in + (size_t)e * K * N;
  u16* dst = outp + (size_t)e * K * N;
  int k0 = blockIdx.y * 64, n0 = blockIdx.x * 64;
  int t = threadIdx.x;
  int kr = t >> 4, nc = (t & 15) * 4;
  #pragma unroll
  for (int rr = 0; rr < 4; rr++) {
    int k = kr + rr * 16;
    float4 v = *(const float4*)(src + (size_t)(k0 + k) * N + n0 + nc);
    tile[nc+0][k] = v.x; tile[nc+1][k] = v.y; tile[nc+2][k] = v.z; tile[nc+3][k] = v.w;
  }
  __syncthreads();
  int n = t >> 2, kc = (t & 3) * 16;
  u32 res[8];
  #pragma unroll
  for (int u = 0; u < 8; u++) {
    u32 lo = f2bf(tile[n][kc + u*2]);
    u32 hi = f2bf(tile[n][kc + u*2 + 1]);
    res[u] = lo | (hi << 16);
  }
  uint4* o = (uint4*)(dst + (size_t)(n0 + n) * K + k0 + kc);
  o[0] = make_uint4(res[0], res[1], res[2], res[3]);
  o[1] = make_uint4(res[4], res[5], res[6], res[7]);
}

// ---- 4. scan: 128-aligned per-expert offsets, per-row-block expert map ----
__global__ void scan_kernel(int* __restrict__ ctrl) {
  __shared__ int so[9];
  if (threadIdx.x == 0) {
    int o = 0;
    for (int e = 0; e < 8; e++) {
      so[e] = o; ctrl[16 + e] = o;
      o += (ctrl[e] + 127) & ~127;
    }
    so[8] = o; ctrl[24] = o;
    for (int e = 0; e < 8; e++) ctrl[8 + e] = 0;   // cursors
  }
  __syncthreads();
  int b = threadIdx.x;
  if (b < NRB) {
    int base = b * 128, ex = -1;
    for (int e = 0; e < 8; e++) if (base >= so[e] && base < so[e+1]) ex = e;
    ctrl[32 + b] = ex;
  }
}

// ---- 5. assign rows ----
__global__ void assign_kernel(const int* __restrict__ tk_idx, const float* __restrict__ tk_w,
                              int* __restrict__ ctrl, int* __restrict__ rowmap,
                              float* __restrict__ roww) {
  int t = blockIdx.x * 256 + threadIdx.x;
  if (t >= T_TOK) return;
  #pragma unroll
  for (int k = 0; k < 2; k++) {
    int e = tk_idx[t*2 + k];
    int slot = atomicAdd(&ctrl[8 + e], 1);
    int r = ctrl[16 + e] + slot;
    rowmap[r] = t;
    roww[r] = tk_w[t*2 + k];
  }
}

// LDS layout note (both GEMMs): tile is [128 rows][32 k] bf16, rows are 64 B.
// k-chunk q (8 bf16 = 16 B) of row r is stored at slot s = q ^ ((r>>1)&3).
// Staging realizes this by permuting the GLOBAL source chunk per lane
// (async16's LDS dest is fixed lane*16); reads invert it. Bank aliasing per
// quarter-wave drops 8-way -> 2-way (free, m136).

// ---- 6. GEMM1: h = gelu(x[rowmap] @ W1[e] + b1[e]), bf16 out ----
__global__ void gemm1_kernel(const u16* __restrict__ xb, const u16* __restrict__ W1t,
                             const float* __restrict__ b1, const int* __restrict__ ctrl,
                             const int* __restrict__ rowmap, u16* __restrict__ h) {
  int rb = blockIdx.y, nb = blockIdx.x;
  int e = ctrl[32 + rb];
  if (e < 0) return;
  __shared__ u16 As[4096];   // [128 rows][32 k] bf16 (chunk-swizzled)
  __shared__ u16 Bs[4096];   // [128 n]  [32 k] bf16 (chunk-swizzled)
  int tid = threadIdx.x, lane = tid & 63, w = tid >> 6;
  int c0 = w, c1 = w + 4;
  int rA0 = c0*16 + (lane >> 2), rA1 = c1*16 + (lane >> 2);
  int colo = (((lane & 3) ^ ((lane >> 3) & 3))) * 8;   // swizzled source k-chunk
  int t0 = rowmap[rb*128 + rA0]; t0 = t0 < 0 ? 0 : t0;
  int t1 = rowmap[rb*128 + rA1]; t1 = t1 < 0 ? 0 : t1;
  const u16* gA0 = xb + (size_t)t0 * DMODEL + colo;
  const u16* gA1 = xb + (size_t)t1 * DMODEL + colo;
  const u16* We  = W1t + (size_t)e * FDIM * DMODEL;
  const u16* gB0 = We + (size_t)(nb*128 + rA0) * DMODEL + colo;
  const u16* gB1 = We + (size_t)(nb*128 + rA1) * DMODEL + colo;
  u16* lA0 = &As[c0*512]; u16* lA1 = &As[c1*512];
  u16* lB0 = &Bs[c0*512]; u16* lB1 = &Bs[c1*512];
  f32x4 acc[4][4];
  f32x4 z = {0.f, 0.f, 0.f, 0.f};
  #pragma unroll
  for (int i = 0; i < 4; i++)
    #pragma unroll
    for (int j = 0; j < 4; j++) acc[i][j] = z;
  int m0 = (w >> 1) * 64, n0 = (w & 1) * 64, q = lane >> 4, cc = lane & 15;
  int sa = (q ^ ((cc >> 1) & 3)) * 8;                  // de-swizzled read slot
  for (int kb = 0; kb < DMODEL / 32; kb++) {
    async16(lA0, gA0); async16(lA1, gA1);
    async16(lB0, gB0); async16(lB1, gB1);
    gA0 += 32; gA1 += 32; gB0 += 32; gB1 += 32;
    __syncthreads();
    short8 af[4], bf[4];
    #pragma unroll
    for (int i = 0; i < 4; i++) af[i] = *(const short8*)&As[(m0 + i*16 + cc)*32 + sa];
    #pragma unroll
    for (int j = 0; j < 4; j++) bf[j] = *(const short8*)&Bs[(n0 + j*16 + cc)*32 + sa];
    #pragma unroll
    for (int i = 0; i < 4; i++)
      #pragma unroll
      for (int j = 0; j < 4; j++)
        acc[i][j] = __builtin_amdgcn_mfma_f32_16x16x32_bf16(af[i], bf[j], acc[i][j], 0, 0, 0);
    __syncthreads();
  }
  float bias[4];
  #pragma unroll
  for (int j = 0; j < 4; j++) bias[j] = b1[e*FDIM + nb*128 + n0 + j*16 + cc];
  #pragma unroll
  for (int i = 0; i < 4; i++)
    #pragma unroll
    for (int j = 0; j < 4; j++) {
      int col = nb*128 + n0 + j*16 + cc;
      #pragma unroll
      for (int r = 0; r < 4; r++) {
        int row = rb*128 + m0 + i*16 + q*4 + r;
        float v = acc[i][j][r] + bias[j];
        h[(size_t)row * FDIM + col] = f2bf(fast_gelu(v));
      }
    }
}

// ---- 7. GEMM2 (split-K=2): out[t] += w * (h @ W2[e] + b2[e]) ----
__global__ void gemm2_kernel(const u16* __restrict__ h, const u16* __restrict__ W2t,
                             const float* __restrict__ b2, const int* __restrict__ ctrl,
                             const int* __restrict__ rowmap, const float* __restrict__ roww,
                             float* __restrict__ out) {
  int rb = blockIdx.y, nb = blockIdx.x, zs = blockIdx.z;
  int e = ctrl[32 + rb];
  if (e < 0) return;
  __shared__ u16 As[4096];
  __shared__ u16 Bs[4096];
  int tid = threadIdx.x, lane = tid & 63, w = tid >> 6;
  int c0 = w, c1 = w + 4;
  int rA0 = c0*16 + (lane >> 2), rA1 = c1*16 + (lane >> 2);
  int colo = (((lane & 3) ^ ((lane >> 3) & 3))) * 8;
  size_t kbase = (size_t)zs * (FDIM / 2);
  const u16* gA0 = h + (size_t)(rb*128 + rA0) * FDIM + kbase + colo;
  const u16* gA1 = h + (size_t)(rb*128 + rA1) * FDIM + kbase + colo;
  const u16* We  = W2t + (size_t)e * DMODEL * FDIM;
  const u16* gB0 = We + (size_t)(nb*128 + rA0) * FDIM + kbase + colo;
  const u16* gB1 = We + (size_t)(nb*128 + rA1) * FDIM + kbase + colo;
  u16* lA0 = &As[c0*512]; u16* lA1 = &As[c1*512];
  u16* lB0 = &Bs[c0*512]; u16* lB1 = &Bs[c1*512];
  f32x4 acc[4][4];
  f32x4 z = {0.f, 0.f, 0.f, 0.f};
  #pragma unroll
  for (int i = 0; i < 4; i++)
    #pragma unroll
    for (int j = 0; j < 4; j++) acc[i][j] = z;
  int m0 = (w >> 1) * 64, n0 = (w & 1) * 64, q = lane >> 4, cc = lane & 15;
  int sa = (q ^ ((cc >> 1) & 3)) * 8;
  for (int kb = 0; kb < FDIM / 2 / 32; kb++) {
    async16(lA0, gA0); async16(lA1, gA1);
    async16(lB0, gB0); async16(lB1, gB1);
    gA0 += 32; gA1 += 32; gB0 += 32; gB1 += 32;
    __syncthreads();
    short8 af[4], bf[4];
    #pragma unroll
    for (int i = 0; i < 4; i++) af[i] = *(const short8*)&As[(m0 + i*16 + cc)*32 + sa];
    #pragma unroll
    for (int j = 0; j < 4; j++) bf[j] = *(const short8*)&Bs[(n0 + j*16 + cc)*32 + sa];
    #pragma unroll
    for (int i = 0; i < 4; i++)
      #pragma unroll
      for (int j = 0; j < 4; j++)
        acc[i][j] = __builtin_amdgcn_mfma_f32_16x16x32_bf16(af[i], bf[j], acc[i][j], 0, 0, 0);
    __syncthreads();
  }
  float bias[4];
  #pragma unroll
  for (int j = 0; j < 4; j++)
    bias[j] = (zs == 0) ? b2[e*DMODEL + nb*128 + n0 + j*16 + cc] : 0.0f;
  #pragma unroll
  for (int i = 0; i < 4; i++)
    #pragma unroll
    for (int r = 0; r < 4; r++) {
      int row = rb*128 + m0 + i*16 + q*4 + r;
      int t = rowmap[row];
      if (t < 0) continue;
      float wgt = roww[row];
      float* orow = out + (size_t)t * DMODEL;
      #pragma unroll
      for (int j = 0; j < 4; j++) {
        int col = nb*128 + n0 + j*16 + cc;
        atomicAdd(orow + col, wgt * (acc[i][j][r] + bias[j]));
      }
    }
}

extern "C" void kernel_launch(void* const* d_in, const int* in_sizes, int n_in,
                              void* d_out, int out_size, void* d_ws, size_t ws_size,
                              hipStream_t stream) {
  const float* x  = (const float*)d_in[0];
  const float* Wr = (const float*)d_in[1];
  const float* br = (const float*)d_in[2];
  const float* W1 = (const float*)d_in[3];
  const float* b1 = (const float*)d_in[4];
  const float* W2 = (const float*)d_in[5];
  const float* b2 = (const float*)d_in[6];
  float* out = (float*)d_out;
  char* ws = (char*)d_ws;
  if (ws_size < WS_NEED) return;

  int*   ctrl   = (int*)(ws + OFF_CTRL);
  int*   rowmap = (int*)(ws + OFF_ROWMAP);
  float* roww   = (float*)(ws + OFF_ROWW);
  int*   tk_idx = (int*)(ws + OFF_TKIDX);
  float* tk_w   = (float*)(ws + OFF_TKW);
  u16*   xb     = (u16*)(ws + OFF_XB);
  u16*   W1t    = (u16*)(ws + OFF_W1T);
  u16*   W2t    = (u16*)(ws + OFF_W2T);
  u16*   hbuf   = (u16*)(ws + OFF_H);

  hipMemsetAsync(out, 0, (size_t)out_size * sizeof(float), stream);
  init_cast_kernel<<<T_TOK*DMODEL/4/256, 256, 0, stream>>>(x, xb, ctrl, rowmap);
  router_kernel<<<T_TOK/4, 256, 0, stream>>>(x, Wr, br, ctrl, tk_idx, tk_w);
  transpose_cast_kernel<<<dim3(FDIM/64, DMODEL/64, NEXP), 256, 0, stream>>>(W1, W1t, DMODEL, FDIM);
  transpose_cast_kernel<<<dim3(DMODEL/64, FDIM/64, NEXP), 256, 0, stream>>>(W2, W2t, FDIM, DMODEL);
  scan_kernel<<<1, 128, 0, stream>>>(ctrl);
  assign_kernel<<<T_TOK/256, 256, 0, stream>>>(tk_idx, tk_w, ctrl, rowmap, roww);
  gemm1_kernel<<<dim3(FDIM/128, NRB), 256, 0, stream>>>(xb, W1t, b1, ctrl, rowmap, hbuf);
  gemm2_kernel<<<dim3(DMODEL/128, NRB, 2), 256, 0, stream>>>(hbuf, W2t, b2, ctrl, rowmap, roww, out);
}

// Round 3
// 702.053 us; speedup vs baseline: 1.0602x; 1.0602x over previous
//
#include <hip/hip_runtime.h>
#include <math.h>

// MoE top-2, D=1024, F=4096, E=8, T=4096 tokens.
// router -> pack rows per expert (128-aligned) -> bf16 grouped GEMM1
// (x @ W1 + b1, GELU) -> bf16 grouped GEMM2 -> y rows -> combine (w0*y0+w1*y1).
// R2: LDS XOR chunk-swizzle (bank conflicts -> 0), fast sigmoid GELU.
// R3: no atomics (y buffer aliased on dead W1T + combine kernel), no split-K,
//     double-buffered LDS with ONE barrier/iter: the vmcnt(0) drain at
//     s_barrier now waits on loads issued a full compute-phase earlier.

#define T_TOK 4096
#define DMODEL 1024
#define FDIM 4096
#define NEXP 8
#define MAXROWS 9216   // sum of round_up(count_e,128) <= 8192 + 8*127 = 9208
#define NRB 72         // MAXROWS / 128

typedef unsigned short u16;
typedef unsigned int u32;
typedef __attribute__((ext_vector_type(8))) short short8;
typedef __attribute__((ext_vector_type(4))) float f32x4;

// ---- workspace layout (bytes) ----
constexpr size_t OFF_CTRL   = 0;
constexpr size_t OFF_ROWMAP = 4096;                             // MAXROWS ints
constexpr size_t OFF_ROWW   = OFF_ROWMAP + (size_t)MAXROWS*4;   // MAXROWS floats
constexpr size_t OFF_TKIDX  = OFF_ROWW + (size_t)MAXROWS*4;     // T*2 ints
constexpr size_t OFF_TKW    = OFF_TKIDX + (size_t)T_TOK*2*4;    // T*2 floats
constexpr size_t OFF_T2R    = OFF_TKW + (size_t)T_TOK*2*4;      // T*2 ints (token->row slot)
constexpr size_t OFF_XB     = 262144;                           // T*D bf16 = 8 MiB
constexpr size_t OFF_W1T    = OFF_XB + (size_t)T_TOK*DMODEL*2;      // E*F*D bf16 (64 MiB)
constexpr size_t OFF_W2T    = OFF_W1T + (size_t)NEXP*DMODEL*FDIM*2; // E*D*F bf16
constexpr size_t OFF_H      = OFF_W2T + (size_t)NEXP*FDIM*DMODEL*2; // MAXROWS*F bf16
constexpr size_t WS_NEED    = OFF_H + (size_t)MAXROWS*FDIM*2;       // ~208 MiB
// y (fp32 MAXROWS*DMODEL = 37.75 MiB) aliases W1T: W1T is dead once gemm1 ran.
constexpr size_t OFF_Y      = OFF_W1T;

__device__ __forceinline__ u16 f2bf(float f) {   // fp32 -> bf16, round-nearest-even
  u32 u = __float_as_uint(f);
  u += 0x7FFFu + ((u >> 16) & 1u);
  return (u16)(u >> 16);
}

__device__ __forceinline__ float fast_gelu(float v) {
  // gelu(v) = v * sigmoid(2u), u = 0.7978845608*(v + 0.044715 v^3); |err|<~5e-4
  float u2 = v * (1.5957691216f + 0.0713548162f * v * v);
  float s = __expf(-u2);
  return v * __builtin_amdgcn_rcpf(1.0f + s);
}

__device__ __forceinline__ void async16(void* lds, const void* g) {
  __builtin_amdgcn_global_load_lds((const __attribute__((address_space(1))) void*)g,
                                   (__attribute__((address_space(3))) void*)lds,
                                   16, 0, 0);
}

// ---- 1. cast x to bf16; init control state ----
__global__ void init_cast_kernel(const float* __restrict__ x, u16* __restrict__ xb,
                                 int* __restrict__ ctrl, int* __restrict__ rowmap) {
  int g = blockIdx.x * 256 + threadIdx.x;
  float4 v = ((const float4*)x)[g];
  u32 p0 = (u32)f2bf(v.x) | ((u32)f2bf(v.y) << 16);
  u32 p1 = (u32)f2bf(v.z) | ((u32)f2bf(v.w) << 16);
  ((uint2*)xb)[g] = make_uint2(p0, p1);
  if (g < NEXP) ctrl[g] = 0;
  if (g < MAXROWS) rowmap[g] = -1;
}

// ---- 2. router: fp32 logits, top-2, softmax ----
__global__ void router_kernel(const float* __restrict__ x, const float* __restrict__ Wr,
                              const float* __restrict__ br, int* __restrict__ ctrl,
                              int* __restrict__ tk_idx, float* __restrict__ tk_w) {
  int lane = threadIdx.x & 63, w = threadIdx.x >> 6;
  int t = blockIdx.x * 4 + w;
  const float* xt = x + (size_t)t * DMODEL;
  float acc[8] = {0.f,0.f,0.f,0.f,0.f,0.f,0.f,0.f};
  for (int i = 0; i < DMODEL / 64; i++) {
    int d = i * 64 + lane;
    float xv = xt[d];
    float4 w0 = *(const float4*)(Wr + d * 8);
    float4 w1 = *(const float4*)(Wr + d * 8 + 4);
    acc[0] += xv * w0.x; acc[1] += xv * w0.y; acc[2] += xv * w0.z; acc[3] += xv * w0.w;
    acc[4] += xv * w1.x; acc[5] += xv * w1.y; acc[6] += xv * w1.z; acc[7] += xv * w1.w;
  }
  #pragma unroll
  for (int off = 32; off > 0; off >>= 1)
    #pragma unroll
    for (int e = 0; e < 8; e++) acc[e] += __shfl_xor(acc[e], off);
  if (lane == 0) {
    float lg[8];
    #pragma unroll
    for (int e = 0; e < 8; e++) lg[e] = acc[e] + br[e];
    int e0 = 0;
    #pragma unroll
    for (int e = 1; e < 8; e++) if (lg[e] > lg[e0]) e0 = e;   // strict >: lowest idx wins ties
    int e1 = -1;
    #pragma unroll
    for (int e = 0; e < 8; e++) if (e != e0 && (e1 < 0 || lg[e] > lg[e1])) e1 = e;
    float p1 = __expf(lg[e1] - lg[e0]);
    float inv = 1.f / (1.f + p1);
    tk_idx[t*2] = e0; tk_idx[t*2+1] = e1;
    tk_w[t*2] = inv;  tk_w[t*2+1] = p1 * inv;
    atomicAdd(&ctrl[e0], 1); atomicAdd(&ctrl[e1], 1);
  }
}

// ---- 3. transpose+cast weights: [E][K][N] fp32 -> [E][N][K] bf16 ----
__global__ void transpose_cast_kernel(const float* __restrict__ in, u16* __restrict__ outp,
                                      int K, int N) {
  __shared__ float tile[64][65];
  int e = blockIdx.z;
  const float* src = in + (size_t)e * K * N;
  u16* dst = outp + (size_t)e * K * N;
  int k0 = blockIdx.y * 64, n0 = blockIdx.x * 64;
  int t = threadIdx.x;
  int kr = t >> 4, nc = (t & 15) * 4;
  #pragma unroll
  for (int rr = 0; rr < 4; rr++) {
    int k = kr + rr * 16;
    float4 v = *(const float4*)(src + (size_t)(k0 + k) * N + n0 + nc);
    tile[nc+0][k] = v.x; tile[nc+1][k] = v.y; tile[nc+2][k] = v.z; tile[nc+3][k] = v.w;
  }
  __syncthreads();
  int n = t >> 2, kc = (t & 3) * 16;
  u32 res[8];
  #pragma unroll
  for (int u = 0; u < 8; u++) {
    u32 lo = f2bf(tile[n][kc + u*2]);
    u32 hi = f2bf(tile[n][kc + u*2 + 1]);
    res[u] = lo | (hi << 16);
  }
  uint4* o = (uint4*)(dst + (size_t)(n0 + n) * K + k0 + kc);
  o[0] = make_uint4(res[0], res[1], res[2], res[3]);
  o[1] = make_uint4(res[4], res[5], res[6], res[7]);
}

// ---- 4. scan: 128-aligned per-expert offsets, per-row-block expert map ----
__global__ void scan_kernel(int* __restrict__ ctrl) {
  __shared__ int so[9];
  if (threadIdx.x == 0) {
    int o = 0;
    for (int e = 0; e < 8; e++) {
      so[e] = o; ctrl[16 + e] = o;
      o += (ctrl[e] + 127) & ~127;
    }
    so[8] = o; ctrl[24] = o;
    for (int e = 0; e < 8; e++) ctrl[8 + e] = 0;   // cursors
  }
  __syncthreads();
  int b = threadIdx.x;
  if (b < NRB) {
    int base = b * 128, ex = -1;
    for (int e = 0; e < 8; e++) if (base >= so[e] && base < so[e+1]) ex = e;
    ctrl[32 + b] = ex;
  }
}

// ---- 5. assign rows ----
__global__ void assign_kernel(const int* __restrict__ tk_idx, const float* __restrict__ tk_w,
                              int* __restrict__ ctrl, int* __restrict__ rowmap,
                              float* __restrict__ roww, int* __restrict__ t2r) {
  int t = blockIdx.x * 256 + threadIdx.x;
  if (t >= T_TOK) return;
  #pragma unroll
  for (int k = 0; k < 2; k++) {
    int e = tk_idx[t*2 + k];
    int slot = atomicAdd(&ctrl[8 + e], 1);
    int r = ctrl[16 + e] + slot;
    rowmap[r] = t;
    roww[r] = tk_w[t*2 + k];
    t2r[t*2 + k] = r;
  }
}

// LDS layout (both GEMMs): [128 rows][32 k] bf16, rows 64 B. k-chunk q (16 B)
// of row r stored at slot q ^ ((r>>1)&3) by permuting the GLOBAL source chunk
// per lane; reads invert. 8-way bank aliasing -> 2-way (free, m136).

// ---- 6. GEMM1: h = gelu(x[rowmap] @ W1[e] + b1[e]), bf16 out ----
__global__ void gemm1_kernel(const u16* __restrict__ xb, const u16* __restrict__ W1t,
                             const float* __restrict__ b1, const int* __restrict__ ctrl,
                             const int* __restrict__ rowmap, u16* __restrict__ h) {
  int rb = blockIdx.y, nb = blockIdx.x;
  int e = ctrl[32 + rb];
  if (e < 0) return;
  __shared__ u16 As[2][4096];
  __shared__ u16 Bs[2][4096];
  int tid = threadIdx.x, lane = tid & 63, w = tid >> 6;
  int c0 = w, c1 = w + 4;
  int rA0 = c0*16 + (lane >> 2), rA1 = c1*16 + (lane >> 2);
  int colo = (((lane & 3) ^ ((lane >> 3) & 3))) * 8;   // swizzled source k-chunk
  int t0 = rowmap[rb*128 + rA0]; t0 = t0 < 0 ? 0 : t0;
  int t1 = rowmap[rb*128 + rA1]; t1 = t1 < 0 ? 0 : t1;
  const u16* gA0 = xb + (size_t)t0 * DMODEL + colo;
  const u16* gA1 = xb + (size_t)t1 * DMODEL + colo;
  const u16* We  = W1t + (size_t)e * FDIM * DMODEL;
  const u16* gB0 = We + (size_t)(nb*128 + rA0) * DMODEL + colo;
  const u16* gB1 = We + (size_t)(nb*128 + rA1) * DMODEL + colo;
  f32x4 acc[4][4];
  f32x4 z = {0.f, 0.f, 0.f, 0.f};
  #pragma unroll
  for (int i = 0; i < 4; i++)
    #pragma unroll
    for (int j = 0; j < 4; j++) acc[i][j] = z;
  int m0 = (w >> 1) * 64, n0 = (w & 1) * 64, q = lane >> 4, cc = lane & 15;
  int sa = (q ^ ((cc >> 1) & 3)) * 8;                  // de-swizzled read slot
  // prologue: stage kb=0 into buf 0
  async16(&As[0][c0*512], gA0); async16(&As[0][c1*512], gA1);
  async16(&Bs[0][c0*512], gB0); async16(&Bs[0][c1*512], gB1);
  gA0 += 32; gA1 += 32; gB0 += 32; gB1 += 32;
  constexpr int NK = DMODEL / 32;
  for (int kb = 0; kb < NK; kb++) {
    int cur = kb & 1;
    __syncthreads();                       // drains cur-buffer loads (issued 1 iter ago)
    if (kb + 1 < NK) {
      int nxt = cur ^ 1;
      async16(&As[nxt][c0*512], gA0); async16(&As[nxt][c1*512], gA1);
      async16(&Bs[nxt][c0*512], gB0); async16(&Bs[nxt][c1*512], gB1);
      gA0 += 32; gA1 += 32; gB0 += 32; gB1 += 32;
    }
    short8 af[4], bf[4];
    #pragma unroll
    for (int i = 0; i < 4; i++) af[i] = *(const short8*)&As[cur][(m0 + i*16 + cc)*32 + sa];
    #pragma unroll
    for (int j = 0; j < 4; j++) bf[j] = *(const short8*)&Bs[cur][(n0 + j*16 + cc)*32 + sa];
    #pragma unroll
    for (int i = 0; i < 4; i++)
      #pragma unroll
      for (int j = 0; j < 4; j++)
        acc[i][j] = __builtin_amdgcn_mfma_f32_16x16x32_bf16(af[i], bf[j], acc[i][j], 0, 0, 0);
  }
  float bias[4];
  #pragma unroll
  for (int j = 0; j < 4; j++) bias[j] = b1[e*FDIM + nb*128 + n0 + j*16 + cc];
  #pragma unroll
  for (int i = 0; i < 4; i++)
    #pragma unroll
    for (int j = 0; j < 4; j++) {
      int col = nb*128 + n0 + j*16 + cc;
      #pragma unroll
      for (int r = 0; r < 4; r++) {
        int row = rb*128 + m0 + i*16 + q*4 + r;
        float v = acc[i][j][r] + bias[j];
        h[(size_t)row * FDIM + col] = f2bf(fast_gelu(v));
      }
    }
}

// ---- 7. GEMM2: y[row] = h[row] @ W2[e] + b2[e]  (no atomics) ----
__global__ void gemm2_kernel(const u16* __restrict__ h, const u16* __restrict__ W2t,
                             const float* __restrict__ b2, const int* __restrict__ ctrl,
                             float* __restrict__ y) {
  int rb = blockIdx.y, nb = blockIdx.x;
  int e = ctrl[32 + rb];
  if (e < 0) return;
  __shared__ u16 As[2][4096];
  __shared__ u16 Bs[2][4096];
  int tid = threadIdx.x, lane = tid & 63, w = tid >> 6;
  int c0 = w, c1 = w + 4;
  int rA0 = c0*16 + (lane >> 2), rA1 = c1*16 + (lane >> 2);
  int colo = (((lane & 3) ^ ((lane >> 3) & 3))) * 8;
  const u16* gA0 = h + (size_t)(rb*128 + rA0) * FDIM + colo;
  const u16* gA1 = h + (size_t)(rb*128 + rA1) * FDIM + colo;
  const u16* We  = W2t + (size_t)e * DMODEL * FDIM;
  const u16* gB0 = We + (size_t)(nb*128 + rA0) * FDIM + colo;
  const u16* gB1 = We + (size_t)(nb*128 + rA1) * FDIM + colo;
  f32x4 acc[4][4];
  f32x4 z = {0.f, 0.f, 0.f, 0.f};
  #pragma unroll
  for (int i = 0; i < 4; i++)
    #pragma unroll
    for (int j = 0; j < 4; j++) acc[i][j] = z;
  int m0 = (w >> 1) * 64, n0 = (w & 1) * 64, q = lane >> 4, cc = lane & 15;
  int sa = (q ^ ((cc >> 1) & 3)) * 8;
  async16(&As[0][c0*512], gA0); async16(&As[0][c1*512], gA1);
  async16(&Bs[0][c0*512], gB0); async16(&Bs[0][c1*512], gB1);
  gA0 += 32; gA1 += 32; gB0 += 32; gB1 += 32;
  constexpr int NK = FDIM / 32;
  for (int kb = 0; kb < NK; kb++) {
    int cur = kb & 1;
    __syncthreads();
    if (kb + 1 < NK) {
      int nxt = cur ^ 1;
      async16(&As[nxt][c0*512], gA0); async16(&As[nxt][c1*512], gA1);
      async16(&Bs[nxt][c0*512], gB0); async16(&Bs[nxt][c1*512], gB1);
      gA0 += 32; gA1 += 32; gB0 += 32; gB1 += 32;
    }
    short8 af[4], bf[4];
    #pragma unroll
    for (int i = 0; i < 4; i++) af[i] = *(const short8*)&As[cur][(m0 + i*16 + cc)*32 + sa];
    #pragma unroll
    for (int j = 0; j < 4; j++) bf[j] = *(const short8*)&Bs[cur][(n0 + j*16 + cc)*32 + sa];
    #pragma unroll
    for (int i = 0; i < 4; i++)
      #pragma unroll
      for (int j = 0; j < 4; j++)
        acc[i][j] = __builtin_amdgcn_mfma_f32_16x16x32_bf16(af[i], bf[j], acc[i][j], 0, 0, 0);
  }
  float bias[4];
  #pragma unroll
  for (int j = 0; j < 4; j++) bias[j] = b2[e*DMODEL + nb*128 + n0 + j*16 + cc];
  #pragma unroll
  for (int i = 0; i < 4; i++)
    #pragma unroll
    for (int r = 0; r < 4; r++) {
      int row = rb*128 + m0 + i*16 + q*4 + r;
      float* yrow = y + (size_t)row * DMODEL;
      #pragma unroll
      for (int j = 0; j < 4; j++) {
        int col = nb*128 + n0 + j*16 + cc;
        yrow[col] = acc[i][j][r] + bias[j];
      }
    }
}

// ---- 8. combine: out[t] = w0*y[r0] + w1*y[r1] ----
__global__ void combine_kernel(const float* __restrict__ y, const int* __restrict__ t2r,
                               const float* __restrict__ tk_w, float* __restrict__ out) {
  int t = blockIdx.x, d4 = threadIdx.x;
  int r0 = t2r[t*2], r1 = t2r[t*2+1];
  float w0 = tk_w[t*2], w1 = tk_w[t*2+1];
  float4 a = ((const float4*)(y + (size_t)r0 * DMODEL))[d4];
  float4 b = ((const float4*)(y + (size_t)r1 * DMODEL))[d4];
  float4 o;
  o.x = w0*a.x + w1*b.x; o.y = w0*a.y + w1*b.y;
  o.z = w0*a.z + w1*b.z; o.w = w0*a.w + w1*b.w;
  ((float4*)(out + (size_t)t * DMODEL))[d4] = o;
}

extern "C" void kernel_launch(void* const* d_in, const int* in_sizes, int n_in,
                              void* d_out, int out_size, void* d_ws, size_t ws_size,
                              hipStream_t stream) {
  const float* x  = (const float*)d_in[0];
  const float* Wr = (const float*)d_in[1];
  const float* br = (const float*)d_in[2];
  const float* W1 = (const float*)d_in[3];
  const float* b1 = (const float*)d_in[4];
  const float* W2 = (const float*)d_in[5];
  const float* b2 = (const float*)d_in[6];
  float* out = (float*)d_out;
  char* ws = (char*)d_ws;
  if (ws_size < WS_NEED) return;

  int*   ctrl   = (int*)(ws + OFF_CTRL);
  int*   rowmap = (int*)(ws + OFF_ROWMAP);
  float* roww   = (float*)(ws + OFF_ROWW);
  int*   tk_idx = (int*)(ws + OFF_TKIDX);
  float* tk_w   = (float*)(ws + OFF_TKW);
  int*   t2r    = (int*)(ws + OFF_T2R);
  u16*   xb     = (u16*)(ws + OFF_XB);
  u16*   W1t    = (u16*)(ws + OFF_W1T);
  u16*   W2t    = (u16*)(ws + OFF_W2T);
  u16*   hbuf   = (u16*)(ws + OFF_H);
  float* ybuf   = (float*)(ws + OFF_Y);   // aliases W1T (dead after gemm1)

  init_cast_kernel<<<T_TOK*DMODEL/4/256, 256, 0, stream>>>(x, xb, ctrl, rowmap);
  router_kernel<<<T_TOK/4, 256, 0, stream>>>(x, Wr, br, ctrl, tk_idx, tk_w);
  transpose_cast_kernel<<<dim3(FDIM/64, DMODEL/64, NEXP), 256, 0, stream>>>(W1, W1t, DMODEL, FDIM);
  transpose_cast_kernel<<<dim3(DMODEL/64, FDIM/64, NEXP), 256, 0, stream>>>(W2, W2t, FDIM, DMODEL);
  scan_kernel<<<1, 128, 0, stream>>>(ctrl);
  assign_kernel<<<T_TOK/256, 256, 0, stream>>>(tk_idx, tk_w, ctrl, rowmap, roww, t2r);
  gemm1_kernel<<<dim3(FDIM/128, NRB), 256, 0, stream>>>(xb, W1t, b1, ctrl, rowmap, hbuf);
  gemm2_kernel<<<dim3(DMODEL/128, NRB), 256, 0, stream>>>(hbuf, W2t, b2, ctrl, ybuf);
  combine_kernel<<<T_TOK, 256, 0, stream>>>(ybuf, t2r, tk_w, out);
}